// Round 1
// baseline (73.475 us; speedup 1.0000x reference)
//
#include <hip/hip_runtime.h>

typedef float f4v __attribute__((ext_vector_type(4)));
typedef float f32x4 __attribute__((ext_vector_type(4)));
typedef __bf16 bf16x8 __attribute__((ext_vector_type(8)));
typedef unsigned short ushort8 __attribute__((ext_vector_type(8)));

static constexpr int BROWS = 256;
static constexpr int NCOLS = 8192;
static constexpr int KDIM  = 2048;

// workspace layout (bytes)
static constexpr size_t OFF_XN      = 0;                                    // ushort [3][256][2048]
static constexpr size_t OFF_PART    = (size_t)3 * 256 * 2048 * 2;           // float [3][256][128][4]
static constexpr size_t OFF_DOTT    = OFF_PART + (size_t)3 * 256 * 128 * 16;// float [768]
static constexpr size_t OFF_ROWLOSS = OFF_DOTT + 768 * 4;                   // float [768]

__device__ __forceinline__ unsigned short f2bf(float x) {
  union { float f; unsigned u; } c; c.f = x;
  unsigned r = c.u + 0x7fffu + ((c.u >> 16) & 1u);   // RNE
  return (unsigned short)(r >> 16);
}

__device__ __forceinline__ void gload_lds16(const void* g, void* l) {
  __builtin_amdgcn_global_load_lds((const __attribute__((address_space(1))) void*)g,
                                   (__attribute__((address_space(3))) void*)l,
                                   16, 0, 0);
}

// ---------------- kernel 1: row-normalize inputs -> bf16 ----------------
__global__ __launch_bounds__(256) void k_normalize(
    const float* __restrict__ x0, const float* __restrict__ x1, const float* __restrict__ x2,
    unsigned short* __restrict__ xn)
{
  int bid = blockIdx.x;            // 0..767 : branch*256 + row
  int branch = bid >> 8;
  int row = bid & 255;
  const float* src = (branch == 0 ? x0 : (branch == 1 ? x1 : x2)) + (size_t)row * KDIM;
  int tid = threadIdx.x;
  f4v a = *(const f4v*)(src + tid * 8);
  f4v b = *(const f4v*)(src + tid * 8 + 4);
  float s = a[0]*a[0] + a[1]*a[1] + a[2]*a[2] + a[3]*a[3]
          + b[0]*b[0] + b[1]*b[1] + b[2]*b[2] + b[3]*b[3];
  #pragma unroll
  for (int m = 1; m < 64; m <<= 1) s += __shfl_xor(s, m);
  __shared__ float ls[4];
  if ((tid & 63) == 0) ls[tid >> 6] = s;
  __syncthreads();
  float total = ls[0] + ls[1] + ls[2] + ls[3];
  float inv = 1.0f / fmaxf(sqrtf(total), 1e-12f);
  ushort8 u;
  #pragma unroll
  for (int e = 0; e < 4; ++e) u[e]     = f2bf(a[e] * inv);
  #pragma unroll
  for (int e = 0; e < 4; ++e) u[4 + e] = f2bf(b[e] * inv);
  *(ushort8*)(xn + (size_t)bid * KDIM + tid * 8) = u;
}

// ---------------- kernel 2: fused GEMM + per-tile reductions ----------------
// BM=256 (all rows), BN=64, BK=64, 4 waves each computing 64x64.
__global__ __launch_bounds__(256, 2) void k_gemm_fused(
    const unsigned short* __restrict__ xn,
    const float* __restrict__ f0, const float* __restrict__ f1, const float* __restrict__ f2,
    const int* __restrict__ targets,
    float* __restrict__ part, float* __restrict__ dotT)
{
  __shared__ unsigned short lA[256 * 64];  // 32 KiB, XOR-swizzled 16B chunks
  __shared__ unsigned short lB[64 * 64];   //  8 KiB, XOR-swizzled 16B chunks

  int bid = blockIdx.x;
  int swz = (bid & 7) * 48 + (bid >> 3);   // XCD-aware swizzle, 384 % 8 == 0 -> bijective
  int branch = swz >> 7;
  int ntile = swz & 127;

  const unsigned short* A = xn + (size_t)branch * (256 * 2048);
  const float* F = (branch == 0 ? f0 : (branch == 1 ? f1 : f2)) + (size_t)ntile * 64 * 2048;

  int tid = threadIdx.x;
  int wave = tid >> 6;
  int lane = tid & 63;

  f32x4 acc[4][4];
  #pragma unroll
  for (int i = 0; i < 4; ++i)
    #pragma unroll
    for (int j = 0; j < 4; ++j)
      #pragma unroll
      for (int q = 0; q < 4; ++q) acc[i][j][q] = 0.0f;

  for (int kt = 0; kt < 32; ++kt) {
    int kbase = kt * 64;
    // B: register-staged f32 loads (issue early, latency hides under A staging)
    f4v bv00, bv01, bv10, bv11;
    {
      int ci = tid;
      int brow = ci >> 3, bc = ci & 7, gc = bc ^ (brow & 7);
      const float* s = F + brow * 2048 + kbase + gc * 8;
      bv00 = *(const f4v*)s; bv01 = *(const f4v*)(s + 4);
    }
    {
      int ci = 256 + tid;
      int brow = ci >> 3, bc = ci & 7, gc = bc ^ (brow & 7);
      const float* s = F + brow * 2048 + kbase + gc * 8;
      bv10 = *(const f4v*)s; bv11 = *(const f4v*)(s + 4);
    }
    // A: async global->LDS, source pre-swizzled so linear LDS dest = swizzled layout
    #pragma unroll
    for (int r = 0; r < 8; ++r) {
      int chunk = r * 256 + tid;
      int arow = chunk >> 3, ac = chunk & 7;
      int gc = ac ^ (arow & 7);
      gload_lds16(A + arow * 2048 + kbase + gc * 8,
                  (char*)lA + (r * 256 + wave * 64) * 16);
    }
    // B: convert f32->bf16, swizzled ds_write_b128
    {
      int brow = tid >> 3, bc = tid & 7;
      ushort8 u;
      #pragma unroll
      for (int e = 0; e < 4; ++e) u[e]     = f2bf(bv00[e]);
      #pragma unroll
      for (int e = 0; e < 4; ++e) u[4 + e] = f2bf(bv01[e]);
      *(ushort8*)(lB + brow * 64 + bc * 8) = u;
    }
    {
      int ci = 256 + tid;
      int brow = ci >> 3, bc = ci & 7;
      ushort8 u;
      #pragma unroll
      for (int e = 0; e < 4; ++e) u[e]     = f2bf(bv10[e]);
      #pragma unroll
      for (int e = 0; e < 4; ++e) u[4 + e] = f2bf(bv11[e]);
      *(ushort8*)(lB + brow * 64 + bc * 8) = u;
    }
    __syncthreads();

    bf16x8 af[4][2], bfr[4][2];
    #pragma unroll
    for (int i = 0; i < 4; ++i)
      #pragma unroll
      for (int ks = 0; ks < 2; ++ks) {
        int row = wave * 64 + i * 16 + (lane & 15);
        int kc = ks * 4 + (lane >> 4);
        af[i][ks] = *(const bf16x8*)(lA + row * 64 + ((kc ^ (row & 7)) << 3));
      }
    #pragma unroll
    for (int j = 0; j < 4; ++j)
      #pragma unroll
      for (int ks = 0; ks < 2; ++ks) {
        int col = j * 16 + (lane & 15);
        int kc = ks * 4 + (lane >> 4);
        bfr[j][ks] = *(const bf16x8*)(lB + col * 64 + ((kc ^ (col & 7)) << 3));
      }
    #pragma unroll
    for (int ks = 0; ks < 2; ++ks)
      #pragma unroll
      for (int i = 0; i < 4; ++i)
        #pragma unroll
        for (int j = 0; j < 4; ++j)
          acc[i][j] = __builtin_amdgcn_mfma_f32_16x16x32_bf16(af[i][ks], bfr[j][ks], acc[i][j], 0, 0, 0);
    __syncthreads();
  }

  // fused epilogue: per-row partials over this 64-col tile.
  // p1 = sum exp(20d-20), Z1 = sum exp(D-2), Z2 = sum exp(2(D-2)), Z3 = sum exp(3(D-2))
  // where D = sqrt(max(2-2d,0)).  C/D layout: col = lane&15, row = (lane>>4)*4 + q.
  int tbase = branch * 256;
  #pragma unroll
  for (int i = 0; i < 4; ++i) {
    #pragma unroll
    for (int q = 0; q < 4; ++q) {
      int row = wave * 64 + i * 16 + ((lane >> 4) << 2) + q;
      int tgt = targets[row];
      float s1 = 0.f, s2 = 0.f, s3 = 0.f, s4 = 0.f;
      #pragma unroll
      for (int j = 0; j < 4; ++j) {
        float d = acc[i][j][q];
        float e1 = __expf(fmaf(20.0f, d, -20.0f));
        float Dv = sqrtf(fmaxf(2.0f - 2.0f * d, 0.0f));
        float e2 = __expf(Dv - 2.0f);
        s1 += e1; s2 += e2;
        float t2 = e2 * e2;
        s3 += t2; s4 += t2 * e2;
        int col = ntile * 64 + j * 16 + (lane & 15);
        if (col == tgt) dotT[tbase + row] = d;   // exactly one writer per row globally
      }
      #pragma unroll
      for (int m = 1; m < 16; m <<= 1) {         // reduce across the 16 lanes sharing this row
        s1 += __shfl_xor(s1, m);
        s2 += __shfl_xor(s2, m);
        s3 += __shfl_xor(s3, m);
        s4 += __shfl_xor(s4, m);
      }
      if ((lane & 15) == 0) {
        f32x4 p; p[0] = s1; p[1] = s2; p[2] = s3; p[3] = s4;
        *(f32x4*)(part + ((size_t)(tbase + row) * 128 + ntile) * 4) = p;
      }
    }
  }
}

// ---------------- kernel 3: combine 128 tile-partials per row -> row loss ----------------
__global__ __launch_bounds__(128) void k_combine(
    const float* __restrict__ part, const float* __restrict__ dotT, float* __restrict__ rowloss)
{
  int row = blockIdx.x;    // 0..767
  int tid = threadIdx.x;   // 128
  f4v p = *(const f4v*)(part + ((size_t)row * 128 + tid) * 4);
  float a0 = p[0], a1 = p[1], a2 = p[2], a3 = p[3];
  #pragma unroll
  for (int m = 1; m < 64; m <<= 1) {
    a0 += __shfl_xor(a0, m); a1 += __shfl_xor(a1, m);
    a2 += __shfl_xor(a2, m); a3 += __shfl_xor(a3, m);
  }
  __shared__ float ls[8];
  if ((tid & 63) == 0) {
    int w = tid >> 6;
    ls[w] = a0; ls[2 + w] = a1; ls[4 + w] = a2; ls[6 + w] = a3;
  }
  __syncthreads();
  if (tid == 0) {
    float p1 = ls[0] + ls[1];
    float Z1 = ls[2] + ls[3];
    float Z2 = ls[4] + ls[5];
    float Z3 = ls[6] + ls[7];
    float dt = dotT[row];
    // CE1 = logsumexp(20*dot) - 20*dot_t   (fixed shift 20 is exact: 20d-20 <= 0)
    float CE1 = 20.0f + logf(p1) - 20.0f * dt;
    // CE2 = log(sum_n exp(S_n)) - S_t ;  sum_n exp(S_n) = N + 1 + Z2/(2 Z1^2) + Z3/(6 Z1^3)
    float Dt = sqrtf(fmaxf(2.0f - 2.0f * dt, 0.0f));
    float St = __expf(Dt - 2.0f) / Z1;
    float sES = 8193.0f + Z2 / (2.0f * Z1 * Z1) + Z3 / (6.0f * Z1 * Z1 * Z1);
    float CE2 = logf(sES) - St;
    rowloss[row] = (CE1 + CE2) * (0.5f / 256.0f);
  }
}

// ---------------- kernel 4: final sum ----------------
__global__ __launch_bounds__(256) void k_final(const float* __restrict__ rowloss, float* __restrict__ out)
{
  int tid = threadIdx.x;
  float v = rowloss[tid] + rowloss[tid + 256] + rowloss[tid + 512];
  #pragma unroll
  for (int m = 1; m < 64; m <<= 1) v += __shfl_xor(v, m);
  __shared__ float ls[4];
  if ((tid & 63) == 0) ls[tid >> 6] = v;
  __syncthreads();
  if (tid == 0) out[0] = ls[0] + ls[1] + ls[2] + ls[3];
}

extern "C" void kernel_launch(void* const* d_in, const int* in_sizes, int n_in,
                              void* d_out, int out_size, void* d_ws, size_t ws_size,
                              hipStream_t stream) {
  const float* in0 = (const float*)d_in[0];
  const float* in1 = (const float*)d_in[1];
  const float* in2 = (const float*)d_in[2];
  const int* targets = (const int*)d_in[3];
  // d_in[4] = epoch (unused by the loss)
  const float* f0 = (const float*)d_in[5];
  const float* f1 = (const float*)d_in[6];
  const float* f2 = (const float*)d_in[7];

  char* ws = (char*)d_ws;
  unsigned short* xn = (unsigned short*)(ws + OFF_XN);
  float* part    = (float*)(ws + OFF_PART);
  float* dotT    = (float*)(ws + OFF_DOTT);
  float* rowloss = (float*)(ws + OFF_ROWLOSS);
  float* out = (float*)d_out;

  k_normalize<<<768, 256, 0, stream>>>(in0, in1, in2, xn);
  k_gemm_fused<<<384, 256, 0, stream>>>(xn, f0, f1, f2, targets, part, dotT);
  k_combine<<<768, 128, 0, stream>>>(part, dotT, rowloss);
  k_final<<<1, 256, 0, stream>>>(rowloss, out);
}